// Round 1
// baseline (354.329 us; speedup 1.0000x reference)
//
#include <hip/hip_runtime.h>
#include <math.h>

namespace {

constexpr int Hh = 112, Ww = 112, Cc = 64, Nn = 16;
constexpr int OHh = 56, OWw = 56;
constexpr float BN_EPS_F = 1e-5f;
constexpr float CLAMP_MIN_F = 1e-4f;

// reflect-pad(1) index map: -1 -> 1, 112 -> 110; clamps garbage (unused) idx into range
__device__ __forceinline__ int reflect_idx(int t) {
    t = t < 0 ? -t : t;
    t = (t >= Hh) ? (2 * Hh - 2 - t) : t;
    return t;
}

// Pass 1: full-res 3x3 conv (64->9 ch), accumulate per-channel sum & sumsq only.
__global__ __launch_bounds__(256) void conv_stats_kernel(
    const float* __restrict__ x, const float* __restrict__ wgt,
    double* __restrict__ stats /* [18]: sum[9], sumsq[9] */)
{
    __shared__ float tile[18 * 18];
    __shared__ float red_sum[4][9];
    __shared__ float red_sq[4][9];

    const int tid = threadIdx.x;
    const int tx = tid & 15, ty = tid >> 4;
    const int n = blockIdx.y;
    const int h0 = (int)(blockIdx.x / 7) * 16;
    const int w0 = (int)(blockIdx.x % 7) * 16;

    float acc[9];
#pragma unroll
    for (int k = 0; k < 9; ++k) acc[k] = 0.f;

    for (int c = 0; c < Cc; ++c) {
        __syncthreads();
        const float* xc = x + ((size_t)(n * Cc + c)) * (Hh * Ww);
        for (int idx = tid; idx < 18 * 18; idx += 256) {
            const int r = idx / 18, cl = idx - r * 18;
            const int gr = reflect_idx(h0 - 1 + r);
            const int gc = reflect_idx(w0 - 1 + cl);
            tile[idx] = xc[gr * Ww + gc];
        }
        __syncthreads();
        float xv[9];
#pragma unroll
        for (int dy = 0; dy < 3; ++dy)
#pragma unroll
            for (int dx = 0; dx < 3; ++dx)
                xv[dy * 3 + dx] = tile[(ty + dy) * 18 + (tx + dx)];
        // weights: uniform address -> scalar loads (s_load), FMA with SGPR operand
        const float* wc = wgt + c * 9;
#pragma unroll
        for (int k = 0; k < 9; ++k) {
            const float* wk = wc + k * (Cc * 9);
#pragma unroll
            for (int t = 0; t < 9; ++t)
                acc[k] = fmaf(wk[t], xv[t], acc[k]);
        }
    }

    // block reduction: wave shuffle -> LDS -> 18 double atomics
    const int lane = tid & 63;
    const int wv = tid >> 6;
#pragma unroll
    for (int k = 0; k < 9; ++k) {
        float s = acc[k];
        float q = acc[k] * acc[k];
#pragma unroll
        for (int off = 32; off > 0; off >>= 1) {
            s += __shfl_down(s, off, 64);
            q += __shfl_down(q, off, 64);
        }
        if (lane == 0) { red_sum[wv][k] = s; red_sq[wv][k] = q; }
    }
    __syncthreads();
    if (tid < 9) {
        float s = red_sum[0][tid] + red_sum[1][tid] + red_sum[2][tid] + red_sum[3][tid];
        float q = red_sq[0][tid] + red_sq[1][tid] + red_sq[2][tid] + red_sq[3][tid];
        atomicAdd(&stats[tid], (double)s);
        atomicAdd(&stats[9 + tid], (double)q);
    }
}

// Pass 2: recompute conv at strided (even) positions, BN+clamp+normalize in regs,
// then 9-tap weighted sum per input channel.
__global__ __launch_bounds__(256) void out_kernel(
    const float* __restrict__ x, const float* __restrict__ wgt,
    const float* __restrict__ gamma, const float* __restrict__ beta,
    const double* __restrict__ stats, float* __restrict__ out)
{
    __shared__ float tile[33 * 33];
    __shared__ float mean_s[9], istd_s[9];

    const int tid = threadIdx.x;
    const int tx = tid & 15, ty = tid >> 4;
    const int n = blockIdx.y;
    const int oh0 = (int)(blockIdx.x / 4) * 16;
    const int ow0 = (int)(blockIdx.x % 4) * 16;
    const int oh = oh0 + ty, ow = ow0 + tx;

    if (tid < 9) {
        const double cnt = (double)Nn * Hh * Ww;
        const double m = stats[tid] / cnt;
        const double v = stats[9 + tid] / cnt - m * m;
        mean_s[tid] = (float)m;
        istd_s[tid] = (float)(1.0 / sqrt(v + (double)BN_EPS_F));
    }

    const int r0 = 2 * oh0 - 1;
    const int c0 = 2 * ow0 - 1;

    float acc[9];
#pragma unroll
    for (int k = 0; k < 9; ++k) acc[k] = 0.f;

    // phase A: conv at this block's strided positions
    for (int c = 0; c < Cc; ++c) {
        __syncthreads();
        const float* xc = x + ((size_t)(n * Cc + c)) * (Hh * Ww);
        for (int idx = tid; idx < 33 * 33; idx += 256) {
            const int r = idx / 33, cl = idx - r * 33;
            const int gr = reflect_idx(r0 + r);
            const int gc = reflect_idx(c0 + cl);
            tile[idx] = xc[gr * Ww + gc];
        }
        __syncthreads();
        float xv[9];
#pragma unroll
        for (int dy = 0; dy < 3; ++dy)
#pragma unroll
            for (int dx = 0; dx < 3; ++dx)
                xv[dy * 3 + dx] = tile[(2 * ty + dy) * 33 + (2 * tx + dx)];
        const float* wc = wgt + c * 9;
#pragma unroll
        for (int k = 0; k < 9; ++k) {
            const float* wk = wc + k * (Cc * 9);
#pragma unroll
            for (int t = 0; t < 9; ++t)
                acc[k] = fmaf(wk[t], xv[t], acc[k]);
        }
    }

    // phase B: BN -> clamp -> normalize over the 9 taps (in registers)
    __syncthreads();
    float sig[9];
    float ssum = 0.f;
#pragma unroll
    for (int k = 0; k < 9; ++k) {
        float v = fmaf((acc[k] - mean_s[k]) * istd_s[k], gamma[k], beta[k]);
        v = fmaxf(v, CLAMP_MIN_F);
        sig[k] = v;
        ssum += v;
    }
    const float inv = 1.f / ssum;
#pragma unroll
    for (int k = 0; k < 9; ++k) sig[k] *= inv;

    const bool active = (oh < OHh) && (ow < OWw);

    // phase C: per-channel 9-tap weighted sum at strided positions
    for (int c = 0; c < Cc; ++c) {
        __syncthreads();
        const float* xc = x + ((size_t)(n * Cc + c)) * (Hh * Ww);
        for (int idx = tid; idx < 33 * 33; idx += 256) {
            const int r = idx / 33, cl = idx - r * 33;
            const int gr = reflect_idx(r0 + r);
            const int gc = reflect_idx(c0 + cl);
            tile[idx] = xc[gr * Ww + gc];
        }
        __syncthreads();
        float o = 0.f;
#pragma unroll
        for (int dy = 0; dy < 3; ++dy)
#pragma unroll
            for (int dx = 0; dx < 3; ++dx)
                o = fmaf(sig[dy * 3 + dx], tile[(2 * ty + dy) * 33 + (2 * tx + dx)], o);
        if (active) out[(((size_t)(n * Cc + c)) * OHh + oh) * OWw + ow] = o;
    }
}

} // namespace

extern "C" void kernel_launch(void* const* d_in, const int* in_sizes, int n_in,
                              void* d_out, int out_size, void* d_ws, size_t ws_size,
                              hipStream_t stream) {
    const float* x     = (const float*)d_in[0];
    const float* wgt   = (const float*)d_in[1];
    const float* gamma = (const float*)d_in[2];
    const float* beta  = (const float*)d_in[3];
    float* out = (float*)d_out;
    double* stats = (double*)d_ws;

    hipMemsetAsync(d_ws, 0, 18 * sizeof(double), stream);
    conv_stats_kernel<<<dim3(49, 16), 256, 0, stream>>>(x, wgt, stats);
    out_kernel<<<dim3(16, 16), 256, 0, stream>>>(x, wgt, gamma, beta, stats, out);
}

// Round 2
// 107.190 us; speedup vs baseline: 3.3056x; 3.3056x over previous
//
#include <hip/hip_runtime.h>
#include <math.h>

namespace {

constexpr int Hh = 112, Ww = 112, Cc = 64, Nn = 16;
constexpr int OHh = 56, OWw = 56;
constexpr float BN_EPS_F = 1e-5f;
constexpr float CLAMP_MIN_F = 1e-4f;
constexpr int TILE_ELEMS = 18 * 18;           // K1 staging tile (16x16 outputs + halo)
constexpr int PLANE_W = 114;                  // K2 padded plane

__device__ __forceinline__ int reflect_idx(int t) {
    t = t < 0 ? -t : t;
    t = (t >= Hh) ? (2 * Hh - 2 - t) : t;
    return t;
}

// K1: full-res 3x3 conv (64ch -> 9 taps). Emits (a) per-tap sum/sumsq stats,
// (b) raw conv values at even (strided) positions into ws as [n][oh][ow][9].
// Channel loop is double-buffered: next channel's tile is loaded to regs
// while computing the current one; single barrier per channel.
__global__ __launch_bounds__(256) void conv_stats_sig_kernel(
    const float* __restrict__ x, const float* __restrict__ wgt,
    double* __restrict__ stats, float* __restrict__ sig_raw)
{
    __shared__ float tile[2][TILE_ELEMS];
    __shared__ float red_sum[4][9];
    __shared__ float red_sq[4][9];

    const int tid = threadIdx.x;
    const int tx = tid & 15, ty = tid >> 4;
    const int n = blockIdx.y;
    const int h0 = (int)(blockIdx.x / 7) * 16;
    const int w0 = (int)(blockIdx.x % 7) * 16;

    // staging addresses (fixed per block): element i0 = tid, i1 = tid + 256
    const int i0 = tid, i1 = tid + 256;
    int g0 = 0, g1 = 0;
    {
        const int r = i0 / 18, cl = i0 - r * 18;
        g0 = reflect_idx(h0 - 1 + r) * Ww + reflect_idx(w0 - 1 + cl);
    }
    if (i1 < TILE_ELEMS) {
        const int r = i1 / 18, cl = i1 - r * 18;
        g1 = reflect_idx(h0 - 1 + r) * Ww + reflect_idx(w0 - 1 + cl);
    }

    const float* xbase = x + (size_t)n * Cc * Hh * Ww;

    // preload channel 0
    tile[0][i0] = xbase[g0];
    if (i1 < TILE_ELEMS) tile[0][i1] = xbase[g1];

    float acc[9];
#pragma unroll
    for (int k = 0; k < 9; ++k) acc[k] = 0.f;

    __syncthreads();

    for (int c = 0; c < Cc; ++c) {
        // issue next channel's global loads (latency hidden under FMAs below)
        float p0 = 0.f, p1 = 0.f;
        if (c + 1 < Cc) {
            const float* xn = xbase + (size_t)(c + 1) * (Hh * Ww);
            p0 = xn[g0];
            if (i1 < TILE_ELEMS) p1 = xn[g1];
        }

        const float* tl = tile[c & 1];
        float xv[9];
#pragma unroll
        for (int dy = 0; dy < 3; ++dy)
#pragma unroll
            for (int dx = 0; dx < 3; ++dx)
                xv[dy * 3 + dx] = tl[(ty + dy) * 18 + (tx + dx)];

        // weights via uniform (scalar) loads
#pragma unroll
        for (int k = 0; k < 9; ++k) {
            const float* wk = wgt + ((size_t)k * Cc + c) * 9;
#pragma unroll
            for (int t = 0; t < 9; ++t)
                acc[k] = fmaf(wk[t], xv[t], acc[k]);
        }

        if (c + 1 < Cc) {
            float* td = tile[(c + 1) & 1];
            td[i0] = p0;
            if (i1 < TILE_ELEMS) td[i1] = p1;
        }
        __syncthreads();
    }

    // store raw sigma at even positions, tap-contiguous layout [n][oh][ow][9]
    if (((ty & 1) == 0) && ((tx & 1) == 0)) {
        const int oh = (h0 + ty) >> 1, ow = (w0 + tx) >> 1;
        float* s = sig_raw + (((size_t)n * OHh + oh) * OWw + ow) * 9;
#pragma unroll
        for (int k = 0; k < 9; ++k) s[k] = acc[k];
    }

    // block reduction of stats
    const int lane = tid & 63;
    const int wv = tid >> 6;
#pragma unroll
    for (int k = 0; k < 9; ++k) {
        float s = acc[k];
        float q = acc[k] * acc[k];
#pragma unroll
        for (int off = 32; off > 0; off >>= 1) {
            s += __shfl_down(s, off, 64);
            q += __shfl_down(q, off, 64);
        }
        if (lane == 0) { red_sum[wv][k] = s; red_sq[wv][k] = q; }
    }
    __syncthreads();
    if (tid < 9) {
        const float s = red_sum[0][tid] + red_sum[1][tid] + red_sum[2][tid] + red_sum[3][tid];
        const float q = red_sq[0][tid] + red_sq[1][tid] + red_sq[2][tid] + red_sq[3][tid];
        atomicAdd(&stats[tid], (double)s);
        atomicAdd(&stats[9 + tid], (double)q);
    }
}

// K2: one block per (n, c) plane. Stage reflect-padded 114x114 x-plane in LDS,
// read raw sigma (tap-contiguous), BN+clamp+normalize in regs, 9-tap LDS FMA,
// coalesced store.
__global__ __launch_bounds__(256) void out_kernel(
    const float* __restrict__ x, const float* __restrict__ sig_raw,
    const float* __restrict__ gamma, const float* __restrict__ beta,
    const double* __restrict__ stats, float* __restrict__ out)
{
    __shared__ float plane[PLANE_W * PLANE_W];
    __shared__ float mean_s[9], istd_s[9], gam_s[9], bet_s[9];

    const int tid = threadIdx.x;
    const int c = blockIdx.x;
    const int n = blockIdx.y;

    if (tid < 9) {
        const double cnt = (double)Nn * Hh * Ww;
        const double m = stats[tid] / cnt;
        const double v = stats[9 + tid] / cnt - m * m;
        mean_s[tid] = (float)m;
        istd_s[tid] = (float)(1.0 / sqrt(v + (double)BN_EPS_F));
        gam_s[tid] = gamma[tid];
        bet_s[tid] = beta[tid];
    }

    const float* xc = x + ((size_t)(n * Cc + c)) * (Hh * Ww);
    for (int idx = tid; idx < PLANE_W * PLANE_W; idx += 256) {
        const int r = idx / PLANE_W, cl = idx - r * PLANE_W;
        plane[idx] = xc[reflect_idx(r - 1) * Ww + reflect_idx(cl - 1)];
    }
    __syncthreads();

    const float* sgn = sig_raw + (size_t)n * OHh * OWw * 9;
    float* outp = out + ((size_t)(n * Cc + c)) * (OHh * OWw);

    for (int p = tid; p < OHh * OWw; p += 256) {
        const int oh = p / OWw, ow = p - oh * OWw;
        const float* sg = sgn + (size_t)p * 9;

        float s[9], ssum = 0.f;
#pragma unroll
        for (int k = 0; k < 9; ++k) {
            float v = fmaf((sg[k] - mean_s[k]) * istd_s[k], gam_s[k], bet_s[k]);
            v = fmaxf(v, CLAMP_MIN_F);
            s[k] = v;
            ssum += v;
        }
        const float inv = 1.f / ssum;

        float o = 0.f;
#pragma unroll
        for (int dy = 0; dy < 3; ++dy)
#pragma unroll
            for (int dx = 0; dx < 3; ++dx)
                o = fmaf(s[dy * 3 + dx], plane[(2 * oh + dy) * PLANE_W + (2 * ow + dx)], o);

        outp[p] = o * inv;
    }
}

} // namespace

extern "C" void kernel_launch(void* const* d_in, const int* in_sizes, int n_in,
                              void* d_out, int out_size, void* d_ws, size_t ws_size,
                              hipStream_t stream) {
    const float* x     = (const float*)d_in[0];
    const float* wgt   = (const float*)d_in[1];
    const float* gamma = (const float*)d_in[2];
    const float* beta  = (const float*)d_in[3];
    float* out = (float*)d_out;

    double* stats = (double*)d_ws;                      // 18 doubles
    float* sig_raw = (float*)((char*)d_ws + 256);       // 16*56*56*9 floats = 1.81 MB

    hipMemsetAsync(d_ws, 0, 256, stream);
    conv_stats_sig_kernel<<<dim3(49, 16), 256, 0, stream>>>(x, wgt, stats, sig_raw);
    out_kernel<<<dim3(64, 16), 256, 0, stream>>>(x, sig_raw, gamma, beta, stats, out);
}